// Round 20
// baseline (250.623 us; speedup 1.0000x reference)
//
#include <hip/hip_runtime.h>
#include <hip/hip_bf16.h>

#define Bb 2
#define Tt 2048
#define Dd 1024
#define Hh 16

typedef short s16x8 __attribute__((ext_vector_type(8)));
typedef float f32x4 __attribute__((ext_vector_type(4)));
typedef unsigned short u16;
typedef short mfma_in_t __attribute__((ext_vector_type(8)));

typedef const __attribute__((address_space(1))) void gvoid;
typedef __attribute__((address_space(3))) void lvoid;

__device__ inline u16 f2bf(float f) {
  union { float f; unsigned u; } v; v.f = f;
  unsigned r = v.u + 0x7FFF + ((v.u >> 16) & 1);
  return (u16)(r >> 16);
}
__device__ inline u16 f2bf_t(float f) {  // truncating: 1 VALU op; rel err <= 2^-8
  return (u16)(__builtin_bit_cast(unsigned, f) >> 16);
}
__device__ inline float bf2f(u16 v) {
  return __builtin_bit_cast(float, (unsigned)v << 16);
}

__device__ inline f32x4 MFMA(s16x8 a, s16x8 b, f32x4 c) {
  return __builtin_amdgcn_mfma_f32_16x16x32_bf16(
      __builtin_bit_cast(mfma_in_t, a), __builtin_bit_cast(mfma_in_t, b), c, 0, 0, 0);
}

// ---------------- LayerNorm: fp32 in -> bf16 out ----------------
__global__ __launch_bounds__(256) void ln_kernel(const float* __restrict__ x,
    const float* __restrict__ w, const float* __restrict__ b, u16* __restrict__ out) {
  int row = blockIdx.x;
  const float4 v = ((const float4*)(x + (size_t)row * Dd))[threadIdx.x];
  float s = v.x + v.y + v.z + v.w;
  float sq = v.x * v.x + v.y * v.y + v.z * v.z + v.w * v.w;
#pragma unroll
  for (int off = 32; off; off >>= 1) { s += __shfl_down(s, off); sq += __shfl_down(sq, off); }
  __shared__ float red[8];
  int wid = threadIdx.x >> 6;
  if ((threadIdx.x & 63) == 0) { red[wid] = s; red[4 + wid] = sq; }
  __syncthreads();
  s = red[0] + red[1] + red[2] + red[3];
  sq = red[4] + red[5] + red[6] + red[7];
  float mean = s * (1.0f / Dd);
  float var = sq * (1.0f / Dd) - mean * mean;
  float rs = rsqrtf(var + 1e-5f);
  float4 wv = ((const float4*)w)[threadIdx.x];
  float4 bv = ((const float4*)b)[threadIdx.x];
  ushort4 o = make_ushort4(f2bf((v.x - mean) * rs * wv.x + bv.x),
                           f2bf((v.y - mean) * rs * wv.y + bv.y),
                           f2bf((v.z - mean) * rs * wv.z + bv.z),
                           f2bf((v.w - mean) * rs * wv.w + bv.w));
  ((ushort4*)(out + (size_t)row * Dd))[threadIdx.x] = o;
}

// ---------------- fused fp32 -> bf16 convert: 6 segments, one launch ----------------
__global__ __launch_bounds__(256) void cvt6_kernel(
    const float* __restrict__ s0, u16* __restrict__ d0,
    const float* __restrict__ s1, u16* __restrict__ d1,
    const float* __restrict__ s2, u16* __restrict__ d2,
    const float* __restrict__ s3, u16* __restrict__ d3,
    const float* __restrict__ s4, u16* __restrict__ d4,
    const float* __restrict__ s5, u16* __restrict__ d5) {
  int blk = blockIdx.x;
  const float* s; u16* d; int base;
  if (blk < 1024)      { s = s0; d = d0; base = blk; }
  else if (blk < 1536) { s = s1; d = d1; base = blk - 1024; }
  else if (blk < 2048) { s = s2; d = d2; base = blk - 1536; }
  else if (blk < 2560) { s = s3; d = d3; base = blk - 2048; }
  else if (blk < 4608) { s = s4; d = d4; base = blk - 2560; }
  else                 { s = s5; d = d5; base = blk - 4608; }
  int i = base * 256 + threadIdx.x;  // 8 elements per thread
  const float4* p = (const float4*)s;
  float4 a = p[i * 2], b2 = p[i * 2 + 1];
  ((ushort4*)d)[i * 2]     = make_ushort4(f2bf(a.x), f2bf(a.y), f2bf(a.z), f2bf(a.w));
  ((ushort4*)d)[i * 2 + 1] = make_ushort4(f2bf(b2.x), f2bf(b2.y), f2bf(b2.z), f2bf(b2.w));
}

// ---------------- GEMM: C[M,N] = A[M,K](bf16) @ W[N,K](bf16)^T ----------------
// Double-buffered global_load_lds pipeline, ONE barrier per BK-step.
// BK=32 for K=1024 shapes (4 blocks/CU); BK=64 only for fc2 (grid 2/CU -> LDS free).
// EPI 0 (qkv): V columns (>=2048) written TRANSPOSED directly to vtout.
template <int EPI, int BN, int BK>
__global__ __launch_bounds__(256, 2) void gemm_bt(
    const u16* __restrict__ A, const u16* __restrict__ W,
    const float* __restrict__ bias, const float* __restrict__ res,
    void* __restrict__ outp, u16* __restrict__ vtout, int K, int ldout) {
  constexpr int MR = (BN == 128) ? 4 : 2;   // 16-row tiles per wave
  constexpr int LPR = BK / 8;               // lanes per staged row
  constexpr int RPC = 512 / BK;             // rows per 512-u16 chunk
  constexpr int CA = (128 * BK) / 512;      // A chunks per buffer
  constexpr int CB = (BN * BK) / 512;       // B chunks per buffer
  __shared__ u16 As[2][128 * BK];  // linear dest, chunk-XOR-swizzled content
  __shared__ u16 Bs[2][BN * BK];
  const int bm = blockIdx.x, bn = blockIdx.y;
  const int t = threadIdx.x, lane = t & 63, w = t >> 6;
  const int l15 = lane & 15, l16 = lane >> 4;
  const int rbase = (BN == 128) ? (w >> 1) * 64 : w * 32;  // wave row base
  const int cbase = (BN == 128) ? (w & 1) * 64 : 0;        // wave col base
  f32x4 acc[MR][4] = {};
  const u16* Abase = A + (size_t)(bm * 128) * K;
  const u16* Wbase = W + (size_t)(bn * BN) * K;
  const int frow = lane / LPR;                                   // row within chunk
  const int fcol = ((lane & (LPR - 1)) ^ (frow & (LPR - 1))) * 8;  // inverse-swizzled source col
#define GEMM_STAGE(k0_, nb_)                                                              \
  _Pragma("unroll")                                                                       \
  for (int i = 0; i < CA / 4; i++) {                                                      \
    int q = w * (CA / 4) + i;                                                             \
    int row = q * RPC + frow;                                                             \
    __builtin_amdgcn_global_load_lds((gvoid*)(Abase + (size_t)row * K + (k0_) + fcol),    \
                                     (lvoid*)&As[nb_][q * 512], 16, 0, 0);                \
  }                                                                                       \
  _Pragma("unroll")                                                                       \
  for (int i = 0; i < CB / 4; i++) {                                                      \
    int q = w * (CB / 4) + i;                                                             \
    int row = q * RPC + frow;                                                             \
    __builtin_amdgcn_global_load_lds((gvoid*)(Wbase + (size_t)row * K + (k0_) + fcol),    \
                                     (lvoid*)&Bs[nb_][q * 512], 16, 0, 0);                \
  }
  GEMM_STAGE(0, 0);
  __syncthreads();
  int cur = 0;
  for (int k0 = 0; k0 < K; k0 += BK) {
    if (k0 + BK < K) { GEMM_STAGE(k0 + BK, cur ^ 1); }
#pragma unroll
    for (int kk = 0; kk < BK / 32; kk++) {
      s16x8 af[MR], bfr[4];
#pragma unroll
      for (int rt = 0; rt < MR; rt++) {
        int ar = rbase + rt * 16 + l15;
        af[rt] = *(const s16x8*)&As[cur][ar * BK + (((kk * 4 + l16) ^ (ar & (LPR - 1))) * 8)];
      }
#pragma unroll
      for (int ct = 0; ct < 4; ct++) {
        int br = cbase + ct * 16 + l15;
        bfr[ct] = *(const s16x8*)&Bs[cur][br * BK + (((kk * 4 + l16) ^ (br & (LPR - 1))) * 8)];
      }
#pragma unroll
      for (int rt = 0; rt < MR; rt++)
#pragma unroll
        for (int ct = 0; ct < 4; ct++)
          acc[rt][ct] = MFMA(af[rt], bfr[ct], acc[rt][ct]);
    }
    __syncthreads();  // implicit vmcnt(0)+lgkmcnt(0): next-buf loads landed, reads done
    cur ^= 1;
  }
  if constexpr (EPI == 0) {
    const int wcb = bn * BN + cbase;  // wave column base (64-aligned -> branch wave-uniform)
    if (wcb >= 2 * Dd) {
      // ---- V segment: write transposed directly to vt[(b*H+h)*64+dd][tok] ----
      const int hb = (wcb - 2 * Dd) >> 6;   // head (uniform per wave)
      const int bb = bm >> 4;               // batch (128-row tiles: 16 per batch)
      u16* vb = vtout + ((size_t)(bb * Hh + hb) * 64) * Tt;
#pragma unroll
      for (int rt = 0; rt < MR; rt++) {
        const int tok0v = (bm & 15) * 128 + rbase + l16 * 4 + rt * 16;
#pragma unroll
        for (int ct = 0; ct < 4; ct++) {
          const int dd = ct * 16 + l15;
          ushort4 pk = make_ushort4(f2bf(acc[rt][ct][0]), f2bf(acc[rt][ct][1]),
                                    f2bf(acc[rt][ct][2]), f2bf(acc[rt][ct][3]));
          *(ushort4*)(vb + (size_t)dd * Tt + tok0v) = pk;
        }
      }
      return;
    }
  }
  const int rg0 = bm * 128 + rbase + l16 * 4;
  const int cg0 = bn * BN + cbase + l15;
#pragma unroll
  for (int rt = 0; rt < MR; rt++) {
#pragma unroll
    for (int ct = 0; ct < 4; ct++) {
#pragma unroll
      for (int j = 0; j < 4; j++) {
        int r = rg0 + rt * 16 + j;
        int c = cg0 + ct * 16;
        float v = acc[rt][ct][j];
        if constexpr (EPI == 0) {
          ((u16*)outp)[(size_t)r * ldout + c] = f2bf(v);
        } else if constexpr (EPI == 1) {
          v += bias[c];
          float u = 0.7978845608f * (v + 0.044715f * v * v * v);
          float th = 1.0f - 2.0f / (__expf(2.0f * u) + 1.0f);
          ((u16*)outp)[(size_t)r * ldout + c] = f2bf(0.5f * v * (1.0f + th));
        } else {
          v += bias[c] + res[(size_t)r * Dd + c];
          ((float*)outp)[(size_t)r * ldout + c] = v;
        }
      }
    }
  }
}

// ---------------- Flash attention with relative-position term ----------------
// r19 base + r20 structural change: Esm DROPPED (Er B-frags read direct from L2 —
// XCD swizzle confines each XCD to 4 (h,b) groups = 1MB Er, L2-resident; the r6
// regression mode was cross-XCD scatter without swizzle). Freed LDS double-buffers
// K/V -> ONE barrier per tile (was 2). Race audit: buf[p] written iter n, re-written
// iter n+2; every wave passed iter n+1's barrier only after finishing iter n's reads.
// Parity counter runs continuously across both passes (boundary case same argument).
// Gsm/P overlay wave-private (no barrier). LDS 47.7KB; VGPR ~96 -> 3 WGs/CU possible.
__global__ __launch_bounds__(256, 2) void attn_kernel(
    const u16* __restrict__ qkv,   // [B*T, 3072] bf16 (q|k|v)
    const u16* __restrict__ erb,   // [H, T, 64] bf16
    const u16* __restrict__ vt,    // [(B*H)*64+d, T] bf16  (V transposed)
    const float* __restrict__ x,
    float* __restrict__ x2) {
  __shared__ u16 Ksm[2][64 * 72];    // [key][hd]  stride 72 u16, double-buffered
  __shared__ u16 Vsm[2][64 * 72];    // [hd][key]  stride 72, double-buffered
  __shared__ u16 Gsm[4][16 * 85];    // per-wave banded QEr (bf16, stride 85); P overlays (stride 72)
  // ---- XCD-aware remap: nwg=512, 64 per XCD = 4 whole (h,b) groups ----
  const int lin = (int)blockIdx.x + 16 * ((int)blockIdx.y + 16 * (int)blockIdx.z);
  const int swz = (lin & 7) * 64 + (lin >> 3);
  const int pairid = swz & 15;
  const int h = (swz >> 4) & 15;
  const int b = swz >> 8;
  const int t = threadIdx.x, lane = t & 63, w = t >> 6;
  const int l15 = lane & 15, l16 = lane >> 4;
  u16* gw = Gsm[w];
  u16* Pw = gw;                      // P overlay (wave-private; written after gw reads)
  const int tr = t >> 3, tc = (t & 7) * 8;
  const u16* kbase = qkv + ((size_t)b * Tt) * 3072 + Dd + h * 64;
  const u16* vbase = vt + ((size_t)(b * Hh + h) * 64) * Tt;
  const u16* ebase = erb + (size_t)h * Tt * 64;
  s16x8 kR0, kR1, vR0, vR1;
#define ATTN_PREFETCH(kjn_)                                                    \
  {                                                                            \
    const int kjn = (kjn_);                                                    \
    kR0 = *(const s16x8*)(kbase + (size_t)(kjn + tr) * 3072 + tc);             \
    kR1 = *(const s16x8*)(kbase + (size_t)(kjn + 32 + tr) * 3072 + tc);        \
    vR0 = *(const s16x8*)(vbase + (size_t)tr * Tt + kjn + tc);                 \
    vR1 = *(const s16x8*)(vbase + (size_t)(32 + tr) * Tt + kjn + tc);          \
  }
  int pbuf = 0;                      // global tile parity (continuous across passes)
  ATTN_PREFETCH(0);
  for (int pass = 0; pass < 2; ++pass) {
    const int qt = pass ? 31 - pairid : pairid;
    const int qi = qt * 64;
    const int nt = qt + 1;
    const int qb = qi + w * 16;      // this wave's q-row base
    const u16* qp = qkv + (size_t)(b * Tt + qb + l15) * 3072 + h * 64 + l16 * 8;
    const s16x8 qf0 = *(const s16x8*)qp;
    const s16x8 qf1 = *(const s16x8*)(qp + 32);
    f32x4 o_acc[4] = {};
    float l_lane[4] = {0.f, 0.f, 0.f, 0.f};
    for (int it = 0; it < nt; ++it) {
      const int kj = it * 64;
      const int cb = pbuf & 1;
      // ---- write prefetched K/V tile into buffer cb ----
      *(s16x8*)&Ksm[cb][tr * 72 + tc] = kR0;
      *(s16x8*)&Ksm[cb][(32 + tr) * 72 + tc] = kR1;
      *(s16x8*)&Vsm[cb][tr * 72 + tc] = vR0;
      *(s16x8*)&Vsm[cb][(32 + tr) * 72 + tc] = vR1;
      __syncthreads();  // the ONLY barrier per tile
      // ---- issue next tile's K/V loads (latency hidden under compute) ----
      if (it + 1 < nt) {
        ATTN_PREFETCH(kj + 64);
      } else if (pass == 0) {
        ATTN_PREFETCH(0);
      }
      // ---- QK^T ----
      f32x4 s_acc[4] = {};
#pragma unroll
      for (int ct = 0; ct < 4; ct++) {
        int col = ct * 16 + l15;
        s16x8 k0 = *(const s16x8*)&Ksm[cb][col * 72 + l16 * 8];
        s16x8 k1 = *(const s16x8*)&Ksm[cb][col * 72 + 32 + l16 * 8];
        s_acc[ct] = MFMA(qf1, k1, MFMA(qf0, k0, s_acc[ct]));
      }
      // ---- banded Q @ Er^T, B-frags direct from global (L2-resident via XCD swizzle) ----
      const int rb2 = Tt - 16 - qb + kj;
#pragma unroll
      for (int gt = 0; gt < 5; gt++) {
        int r = rb2 + gt * 16 + l15;
        r = (r > Tt - 1) ? Tt - 1 : r;  // OOB rows feed masked entries only
        const u16* ep = ebase + (size_t)r * 64 + l16 * 8;
        s16x8 e0 = *(const s16x8*)ep;
        s16x8 e1 = *(const s16x8*)(ep + 32);
        f32x4 z = {};
        f32x4 ga = MFMA(qf1, e1, MFMA(qf0, e0, z));
#pragma unroll
        for (int j = 0; j < 4; j++) gw[(l16 * 4 + j) * 85 + gt * 16 + l15] = f2bf_t(ga[j]);
      }
      // ---- fixed-max softmax: p = exp(logit - 8); no reduces, no rescale ----
      float p[4][4];
      if (kj + 63 <= qb) {  // wave-uniform fast path: tile entirely causal-valid
#pragma unroll
        for (int j = 0; j < 4; j++) {
          const int di = l16 * 4 + j;
          float lacc = 0.f;
#pragma unroll
          for (int ct = 0; ct < 4; ct++) {
            int dj = ct * 16 + l15;
            float pe = __expf((s_acc[ct][j] + bf2f(gw[di * 85 + dj - di + 15])) * 0.125f - 8.0f);
            p[j][ct] = pe;
            lacc += pe;
          }
          l_lane[j] += lacc;
        }
      } else {  // diagonal tile: per-element causal mask
#pragma unroll
        for (int j = 0; j < 4; j++) {
          const int di = l16 * 4 + j;
          const int ig = qb + di;
          float lacc = 0.f;
#pragma unroll
          for (int ct = 0; ct < 4; ct++) {
            int dj = ct * 16 + l15;
            float pe = 0.f;
            if (kj + dj <= ig)
              pe = __expf((s_acc[ct][j] + bf2f(gw[di * 85 + dj - di + 15])) * 0.125f - 8.0f);
            p[j][ct] = pe;
            lacc += pe;
          }
          l_lane[j] += lacc;
        }
      }
      // ---- P -> wave-private overlay (stride 72, 16B-aligned b128 reads), PV ----
#pragma unroll
      for (int j = 0; j < 4; j++)
#pragma unroll
        for (int ct = 0; ct < 4; ct++)
          Pw[(l16 * 4 + j) * 72 + ct * 16 + l15] = f2bf_t(p[j][ct]);
      s16x8 pa0 = *(const s16x8*)&Pw[l15 * 72 + l16 * 8];
      s16x8 pa1 = *(const s16x8*)&Pw[l15 * 72 + 32 + l16 * 8];
#pragma unroll
      for (int g = 0; g < 4; g++) {
        s16x8 v0 = *(const s16x8*)&Vsm[cb][(g * 16 + l15) * 72 + l16 * 8];
        s16x8 v1 = *(const s16x8*)&Vsm[cb][(g * 16 + l15) * 72 + 32 + l16 * 8];
        o_acc[g] = MFMA(pa1, v1, MFMA(pa0, v0, o_acc[g]));
      }
      ++pbuf;  // no end-of-tile barrier: dbuf + next iter's top barrier covers reuse
    }
    // ---- epilogue: single 16-lane reduce of l, then x2 = x + attn ----
#pragma unroll
    for (int j = 0; j < 4; j++) {
#pragma unroll
      for (int o = 1; o < 16; o <<= 1) l_lane[j] += __shfl_xor(l_lane[j], o);
    }
#pragma unroll
    for (int g = 0; g < 4; g++)
#pragma unroll
      for (int j = 0; j < 4; j++) {
        int r = qb + l16 * 4 + j;
        int c = h * 64 + g * 16 + l15;
        size_t idx = (size_t)(b * Tt + r) * Dd + c;
        x2[idx] = x[idx] + o_acc[g][j] / l_lane[j];
      }
  }
}

extern "C" void kernel_launch(void* const* d_in, const int* in_sizes, int n_in,
                              void* d_out, int out_size, void* d_ws, size_t ws_size,
                              hipStream_t stream) {
  const float* x     = (const float*)d_in[0];
  const float* wq    = (const float*)d_in[1];
  const float* wk    = (const float*)d_in[2];
  const float* wv    = (const float*)d_in[3];
  const float* Er    = (const float*)d_in[4];
  const float* fc1_w = (const float*)d_in[5];
  const float* fc1_b = (const float*)d_in[6];
  const float* fc2_w = (const float*)d_in[7];
  const float* fc2_b = (const float*)d_in[8];
  const float* ln1_w = (const float*)d_in[9];
  const float* ln1_b = (const float*)d_in[10];
  const float* ln2_w = (const float*)d_in[11];
  const float* ln2_b = (const float*)d_in[12];

  const size_t MB = 1024 * 1024;
  char* ws = (char*)d_ws;
  u16*   h1   = (u16*)ws;                 // 0..8M    ln out (reused for ln2 out)
  u16*   qkv  = (u16*)(ws + 8 * MB);      // 8..32M   dead after attn (V third unused)
  u16*   vtb  = (u16*)(ws + 32 * MB);     // 32..40M  dead after attn
  u16*   erb  = (u16*)(ws + 40 * MB);     // 40..44M  dead after attn
  float* x2   = (float*)(ws + 44 * MB);   // 44..60M  alive to end
  u16*   wqkb = (u16*)(ws + 60 * MB);     // 60..66M  [3072,1024] bf16
  u16*   f1b  = (u16*)(ws + 66 * MB);     // 66..74M  [4096,1024] bf16
  u16*   f2b  = (u16*)(ws + 74 * MB);     // 74..82M  [1024,4096] bf16
  u16*   a1   = (u16*)(ws + 8 * MB);      // 8..40M   overlays qkv+vt (both dead)
  float* out  = (float*)d_out;

  ln_kernel<<<dim3(Bb * Tt), 256, 0, stream>>>(x, ln1_w, ln1_b, h1);
  cvt6_kernel<<<dim3(6656), 256, 0, stream>>>(
      Er, erb, wq, wqkb, wk, wqkb + 1024 * 1024, wv, wqkb + 2 * 1024 * 1024,
      fc1_w, f1b, fc2_w, f2b);
  gemm_bt<0, 128, 32><<<dim3(32, 24), 256, 0, stream>>>(h1, wqkb, nullptr, nullptr, qkv, vtb, Dd, 3072);
  attn_kernel<<<dim3(16, 16, 2), 256, 0, stream>>>(qkv, erb, vtb, x, x2);
  ln_kernel<<<dim3(Bb * Tt), 256, 0, stream>>>(x2, ln2_w, ln2_b, h1);
  gemm_bt<1, 128, 32><<<dim3(32, 32), 256, 0, stream>>>(h1, f1b, fc1_b, nullptr, a1, nullptr, Dd, 4096);
  gemm_bt<2, 64, 64><<<dim3(32, 16), 256, 0, stream>>>(a1, f2b, fc2_b, x2, out, nullptr, 4096, Dd);
}

// Round 21
// 238.739 us; speedup vs baseline: 1.0498x; 1.0498x over previous
//
#include <hip/hip_runtime.h>
#include <hip/hip_bf16.h>

#define Bb 2
#define Tt 2048
#define Dd 1024
#define Hh 16

typedef short s16x8 __attribute__((ext_vector_type(8)));
typedef float f32x4 __attribute__((ext_vector_type(4)));
typedef unsigned short u16;
typedef short mfma_in_t __attribute__((ext_vector_type(8)));

typedef const __attribute__((address_space(1))) void gvoid;
typedef __attribute__((address_space(3))) void lvoid;

__device__ inline u16 f2bf(float f) {
  union { float f; unsigned u; } v; v.f = f;
  unsigned r = v.u + 0x7FFF + ((v.u >> 16) & 1);
  return (u16)(r >> 16);
}
__device__ inline u16 f2bf_t(float f) {  // truncating: 1 VALU op; rel err <= 2^-8
  return (u16)(__builtin_bit_cast(unsigned, f) >> 16);
}
__device__ inline float bf2f(u16 v) {
  return __builtin_bit_cast(float, (unsigned)v << 16);
}

__device__ inline f32x4 MFMA(s16x8 a, s16x8 b, f32x4 c) {
  return __builtin_amdgcn_mfma_f32_16x16x32_bf16(
      __builtin_bit_cast(mfma_in_t, a), __builtin_bit_cast(mfma_in_t, b), c, 0, 0, 0);
}

// ---------------- LayerNorm: fp32 in -> bf16 out ----------------
__global__ __launch_bounds__(256) void ln_kernel(const float* __restrict__ x,
    const float* __restrict__ w, const float* __restrict__ b, u16* __restrict__ out) {
  int row = blockIdx.x;
  const float4 v = ((const float4*)(x + (size_t)row * Dd))[threadIdx.x];
  float s = v.x + v.y + v.z + v.w;
  float sq = v.x * v.x + v.y * v.y + v.z * v.z + v.w * v.w;
#pragma unroll
  for (int off = 32; off; off >>= 1) { s += __shfl_down(s, off); sq += __shfl_down(sq, off); }
  __shared__ float red[8];
  int wid = threadIdx.x >> 6;
  if ((threadIdx.x & 63) == 0) { red[wid] = s; red[4 + wid] = sq; }
  __syncthreads();
  s = red[0] + red[1] + red[2] + red[3];
  sq = red[4] + red[5] + red[6] + red[7];
  float mean = s * (1.0f / Dd);
  float var = sq * (1.0f / Dd) - mean * mean;
  float rs = rsqrtf(var + 1e-5f);
  float4 wv = ((const float4*)w)[threadIdx.x];
  float4 bv = ((const float4*)b)[threadIdx.x];
  ushort4 o = make_ushort4(f2bf((v.x - mean) * rs * wv.x + bv.x),
                           f2bf((v.y - mean) * rs * wv.y + bv.y),
                           f2bf((v.z - mean) * rs * wv.z + bv.z),
                           f2bf((v.w - mean) * rs * wv.w + bv.w));
  ((ushort4*)(out + (size_t)row * Dd))[threadIdx.x] = o;
}

// ---------------- fused fp32 -> bf16 convert: 6 segments, one launch ----------------
__global__ __launch_bounds__(256) void cvt6_kernel(
    const float* __restrict__ s0, u16* __restrict__ d0,
    const float* __restrict__ s1, u16* __restrict__ d1,
    const float* __restrict__ s2, u16* __restrict__ d2,
    const float* __restrict__ s3, u16* __restrict__ d3,
    const float* __restrict__ s4, u16* __restrict__ d4,
    const float* __restrict__ s5, u16* __restrict__ d5) {
  int blk = blockIdx.x;
  const float* s; u16* d; int base;
  if (blk < 1024)      { s = s0; d = d0; base = blk; }
  else if (blk < 1536) { s = s1; d = d1; base = blk - 1024; }
  else if (blk < 2048) { s = s2; d = d2; base = blk - 1536; }
  else if (blk < 2560) { s = s3; d = d3; base = blk - 2048; }
  else if (blk < 4608) { s = s4; d = d4; base = blk - 2560; }
  else                 { s = s5; d = d5; base = blk - 4608; }
  int i = base * 256 + threadIdx.x;  // 8 elements per thread
  const float4* p = (const float4*)s;
  float4 a = p[i * 2], b2 = p[i * 2 + 1];
  ((ushort4*)d)[i * 2]     = make_ushort4(f2bf(a.x), f2bf(a.y), f2bf(a.z), f2bf(a.w));
  ((ushort4*)d)[i * 2 + 1] = make_ushort4(f2bf(b2.x), f2bf(b2.y), f2bf(b2.z), f2bf(b2.w));
}

// ---------------- GEMM: C[M,N] = A[M,K](bf16) @ W[N,K](bf16)^T ----------------
// Double-buffered global_load_lds pipeline, ONE barrier per BK-step.
// BK=32 for K=1024 shapes (4 blocks/CU); BK=64 only for fc2 (grid 2/CU -> LDS free).
// EPI 0 (qkv): V columns (>=2048) written TRANSPOSED directly to vtout.
template <int EPI, int BN, int BK>
__global__ __launch_bounds__(256, 2) void gemm_bt(
    const u16* __restrict__ A, const u16* __restrict__ W,
    const float* __restrict__ bias, const float* __restrict__ res,
    void* __restrict__ outp, u16* __restrict__ vtout, int K, int ldout) {
  constexpr int MR = (BN == 128) ? 4 : 2;   // 16-row tiles per wave
  constexpr int LPR = BK / 8;               // lanes per staged row
  constexpr int RPC = 512 / BK;             // rows per 512-u16 chunk
  constexpr int CA = (128 * BK) / 512;      // A chunks per buffer
  constexpr int CB = (BN * BK) / 512;       // B chunks per buffer
  __shared__ u16 As[2][128 * BK];  // linear dest, chunk-XOR-swizzled content
  __shared__ u16 Bs[2][BN * BK];
  const int bm = blockIdx.x, bn = blockIdx.y;
  const int t = threadIdx.x, lane = t & 63, w = t >> 6;
  const int l15 = lane & 15, l16 = lane >> 4;
  const int rbase = (BN == 128) ? (w >> 1) * 64 : w * 32;  // wave row base
  const int cbase = (BN == 128) ? (w & 1) * 64 : 0;        // wave col base
  f32x4 acc[MR][4] = {};
  const u16* Abase = A + (size_t)(bm * 128) * K;
  const u16* Wbase = W + (size_t)(bn * BN) * K;
  const int frow = lane / LPR;                                   // row within chunk
  const int fcol = ((lane & (LPR - 1)) ^ (frow & (LPR - 1))) * 8;  // inverse-swizzled source col
#define GEMM_STAGE(k0_, nb_)                                                              \
  _Pragma("unroll")                                                                       \
  for (int i = 0; i < CA / 4; i++) {                                                      \
    int q = w * (CA / 4) + i;                                                             \
    int row = q * RPC + frow;                                                             \
    __builtin_amdgcn_global_load_lds((gvoid*)(Abase + (size_t)row * K + (k0_) + fcol),    \
                                     (lvoid*)&As[nb_][q * 512], 16, 0, 0);                \
  }                                                                                       \
  _Pragma("unroll")                                                                       \
  for (int i = 0; i < CB / 4; i++) {                                                      \
    int q = w * (CB / 4) + i;                                                             \
    int row = q * RPC + frow;                                                             \
    __builtin_amdgcn_global_load_lds((gvoid*)(Wbase + (size_t)row * K + (k0_) + fcol),    \
                                     (lvoid*)&Bs[nb_][q * 512], 16, 0, 0);                \
  }
  GEMM_STAGE(0, 0);
  __syncthreads();
  int cur = 0;
  for (int k0 = 0; k0 < K; k0 += BK) {
    if (k0 + BK < K) { GEMM_STAGE(k0 + BK, cur ^ 1); }
#pragma unroll
    for (int kk = 0; kk < BK / 32; kk++) {
      s16x8 af[MR], bfr[4];
#pragma unroll
      for (int rt = 0; rt < MR; rt++) {
        int ar = rbase + rt * 16 + l15;
        af[rt] = *(const s16x8*)&As[cur][ar * BK + (((kk * 4 + l16) ^ (ar & (LPR - 1))) * 8)];
      }
#pragma unroll
      for (int ct = 0; ct < 4; ct++) {
        int br = cbase + ct * 16 + l15;
        bfr[ct] = *(const s16x8*)&Bs[cur][br * BK + (((kk * 4 + l16) ^ (br & (LPR - 1))) * 8)];
      }
#pragma unroll
      for (int rt = 0; rt < MR; rt++)
#pragma unroll
        for (int ct = 0; ct < 4; ct++)
          acc[rt][ct] = MFMA(af[rt], bfr[ct], acc[rt][ct]);
    }
    __syncthreads();  // implicit vmcnt(0)+lgkmcnt(0): next-buf loads landed, reads done
    cur ^= 1;
  }
  if constexpr (EPI == 0) {
    const int wcb = bn * BN + cbase;  // wave column base (64-aligned -> branch wave-uniform)
    if (wcb >= 2 * Dd) {
      // ---- V segment: write transposed directly to vt[(b*H+h)*64+dd][tok] ----
      const int hb = (wcb - 2 * Dd) >> 6;   // head (uniform per wave)
      const int bb = bm >> 4;               // batch (128-row tiles: 16 per batch)
      u16* vb = vtout + ((size_t)(bb * Hh + hb) * 64) * Tt;
#pragma unroll
      for (int rt = 0; rt < MR; rt++) {
        const int tok0v = (bm & 15) * 128 + rbase + l16 * 4 + rt * 16;
#pragma unroll
        for (int ct = 0; ct < 4; ct++) {
          const int dd = ct * 16 + l15;
          ushort4 pk = make_ushort4(f2bf(acc[rt][ct][0]), f2bf(acc[rt][ct][1]),
                                    f2bf(acc[rt][ct][2]), f2bf(acc[rt][ct][3]));
          *(ushort4*)(vb + (size_t)dd * Tt + tok0v) = pk;
        }
      }
      return;
    }
  }
  const int rg0 = bm * 128 + rbase + l16 * 4;
  const int cg0 = bn * BN + cbase + l15;
#pragma unroll
  for (int rt = 0; rt < MR; rt++) {
#pragma unroll
    for (int ct = 0; ct < 4; ct++) {
#pragma unroll
      for (int j = 0; j < 4; j++) {
        int r = rg0 + rt * 16 + j;
        int c = cg0 + ct * 16;
        float v = acc[rt][ct][j];
        if constexpr (EPI == 0) {
          ((u16*)outp)[(size_t)r * ldout + c] = f2bf(v);
        } else if constexpr (EPI == 1) {
          v += bias[c];
          float u = 0.7978845608f * (v + 0.044715f * v * v * v);
          float th = 1.0f - 2.0f / (__expf(2.0f * u) + 1.0f);
          ((u16*)outp)[(size_t)r * ldout + c] = f2bf(0.5f * v * (1.0f + th));
        } else {
          v += bias[c] + res[(size_t)r * Dd + c];
          ((float*)outp)[(size_t)r * ldout + c] = v;
        }
      }
    }
  }
}

// ---------------- Flash attention with relative-position term ----------------
// r19 converged structure (best measured: 238.9us total). 256 thr, paired q-blocks
// (qt, 31-qt) 34-tile flat chain, 2 WGs/CU, reg-prefetch one tile ahead (K/V/Er),
// staged Esm (r20 A/B: Er-direct-from-L2 costs +8us — scattered loads land on the
// serial path; staging amortizes them through the prefetch pipeline), fixed-max
// softmax p = exp(logit-8), truncating bf16 Gsm/P stores, Gsm stride 85 / P stride 72,
// XCD swizzle. No setprio; plain __expf.
__global__ __launch_bounds__(256, 2) void attn_kernel(
    const u16* __restrict__ qkv,   // [B*T, 3072] bf16 (q|k|v)
    const u16* __restrict__ erb,   // [H, T, 64] bf16
    const u16* __restrict__ vt,    // [(B*H)*64+d, T] bf16  (V transposed)
    const float* __restrict__ x,
    float* __restrict__ x2) {
  __shared__ u16 Ksm[64 * 72];       // [key][hd]  stride 72 u16 (144B)
  __shared__ u16 Vsm[64 * 72];       // [hd][key]  stride 72
  __shared__ u16 Esm[128 * 72];      // Er band [128 rows][hd]
  __shared__ u16 Gsm[4][16 * 85];    // per-wave banded QEr (bf16, stride 85); P overlays (stride 72)
  // ---- XCD-aware remap: nwg=512, 64 per XCD = 4 whole (h,b) groups ----
  const int lin = (int)blockIdx.x + 16 * ((int)blockIdx.y + 16 * (int)blockIdx.z);
  const int swz = (lin & 7) * 64 + (lin >> 3);
  const int pairid = swz & 15;
  const int h = (swz >> 4) & 15;
  const int b = swz >> 8;
  const int t = threadIdx.x, lane = t & 63, w = t >> 6;
  const int l15 = lane & 15, l16 = lane >> 4;
  u16* gw = Gsm[w];
  u16* Pw = gw;                      // P overlay (wave-private; written after gw reads)
  const int tr = t >> 3, tc = (t & 7) * 8;
  const u16* kbase = qkv + ((size_t)b * Tt) * 3072 + Dd + h * 64;
  const u16* vbase = vt + ((size_t)(b * Hh + h) * 64) * Tt;
  const u16* ebase = erb + (size_t)h * Tt * 64;
  s16x8 kR0, kR1, vR0, vR1, eR0, eR1, eR2, eR3;
#define ATTN_PREFETCH(kjn_, qin_)                                              \
  {                                                                            \
    const int kjn = (kjn_);                                                    \
    kR0 = *(const s16x8*)(kbase + (size_t)(kjn + tr) * 3072 + tc);             \
    kR1 = *(const s16x8*)(kbase + (size_t)(kjn + 32 + tr) * 3072 + tc);        \
    vR0 = *(const s16x8*)(vbase + (size_t)tr * Tt + kjn + tc);                 \
    vR1 = *(const s16x8*)(vbase + (size_t)(32 + tr) * Tt + kjn + tc);          \
    const int rlo = Tt - 64 - (qin_) + kjn;                                    \
    int g0 = rlo + tr;          g0 = g0 > Tt - 1 ? Tt - 1 : g0;                \
    int g1 = rlo + 32 + tr;     g1 = g1 > Tt - 1 ? Tt - 1 : g1;                \
    int g2 = rlo + 64 + tr;     g2 = g2 > Tt - 1 ? Tt - 1 : g2;                \
    int g3 = rlo + 96 + tr;     g3 = g3 > Tt - 1 ? Tt - 1 : g3;                \
    eR0 = *(const s16x8*)(ebase + (size_t)g0 * 64 + tc);                       \
    eR1 = *(const s16x8*)(ebase + (size_t)g1 * 64 + tc);                       \
    eR2 = *(const s16x8*)(ebase + (size_t)g2 * 64 + tc);                       \
    eR3 = *(const s16x8*)(ebase + (size_t)g3 * 64 + tc);                       \
  }
  for (int pass = 0; pass < 2; ++pass) {
    const int qt = pass ? 31 - pairid : pairid;
    const int qi = qt * 64;
    const int nt = qt + 1;
    const int qb = qi + w * 16;      // this wave's q-row base
    const u16* qp = qkv + (size_t)(b * Tt + qb + l15) * 3072 + h * 64 + l16 * 8;
    const s16x8 qf0 = *(const s16x8*)qp;
    const s16x8 qf1 = *(const s16x8*)(qp + 32);
    f32x4 o_acc[4] = {};
    float l_lane[4] = {0.f, 0.f, 0.f, 0.f};
    if (pass == 0) { ATTN_PREFETCH(0, qi); }  // pass-1 first tile prefetched at end of pass-0
    for (int it = 0; it < nt; ++it) {
      const int kj = it * 64;
      // ---- write prefetched tile to LDS ----
      *(s16x8*)&Ksm[tr * 72 + tc] = kR0;
      *(s16x8*)&Ksm[(32 + tr) * 72 + tc] = kR1;
      *(s16x8*)&Vsm[tr * 72 + tc] = vR0;
      *(s16x8*)&Vsm[(32 + tr) * 72 + tc] = vR1;
      *(s16x8*)&Esm[tr * 72 + tc] = eR0;
      *(s16x8*)&Esm[(32 + tr) * 72 + tc] = eR1;
      *(s16x8*)&Esm[(64 + tr) * 72 + tc] = eR2;
      *(s16x8*)&Esm[(96 + tr) * 72 + tc] = eR3;
      __syncthreads();
      // ---- issue next tile's loads (latency hidden under compute below) ----
      if (it + 1 < nt) {
        ATTN_PREFETCH(kj + 64, qi);
      } else if (pass == 0) {
        ATTN_PREFETCH(0, (31 - pairid) * 64);
      }
      // ---- QK^T ----
      f32x4 s_acc[4] = {};
#pragma unroll
      for (int ct = 0; ct < 4; ct++) {
        int col = ct * 16 + l15;
        s16x8 k0 = *(const s16x8*)&Ksm[col * 72 + l16 * 8];
        s16x8 k1 = *(const s16x8*)&Ksm[col * 72 + 32 + l16 * 8];
        s_acc[ct] = MFMA(qf1, k1, MFMA(qf0, k0, s_acc[ct]));
      }
      // ---- banded Q @ Er^T from Esm -> wave-private Gsm (bf16, stride 85) ----
      const int ub = 48 - 16 * w;
#pragma unroll
      for (int gt = 0; gt < 5; gt++) {
        int ur = ub + gt * 16 + l15;
        s16x8 e0 = *(const s16x8*)&Esm[ur * 72 + l16 * 8];
        s16x8 e1 = *(const s16x8*)&Esm[ur * 72 + 32 + l16 * 8];
        f32x4 z = {};
        f32x4 ga = MFMA(qf1, e1, MFMA(qf0, e0, z));
#pragma unroll
        for (int j = 0; j < 4; j++) gw[(l16 * 4 + j) * 85 + gt * 16 + l15] = f2bf_t(ga[j]);
      }
      // ---- fixed-max softmax: p = exp(logit - 8); no reduces, no rescale ----
      float p[4][4];
      if (kj + 63 <= qb) {  // wave-uniform fast path: tile entirely causal-valid
#pragma unroll
        for (int j = 0; j < 4; j++) {
          const int di = l16 * 4 + j;
          float lacc = 0.f;
#pragma unroll
          for (int ct = 0; ct < 4; ct++) {
            int dj = ct * 16 + l15;
            float pe = __expf((s_acc[ct][j] + bf2f(gw[di * 85 + dj - di + 15])) * 0.125f - 8.0f);
            p[j][ct] = pe;
            lacc += pe;
          }
          l_lane[j] += lacc;
        }
      } else {  // diagonal tile: per-element causal mask
#pragma unroll
        for (int j = 0; j < 4; j++) {
          const int di = l16 * 4 + j;
          const int ig = qb + di;
          float lacc = 0.f;
#pragma unroll
          for (int ct = 0; ct < 4; ct++) {
            int dj = ct * 16 + l15;
            float pe = 0.f;
            if (kj + dj <= ig)
              pe = __expf((s_acc[ct][j] + bf2f(gw[di * 85 + dj - di + 15])) * 0.125f - 8.0f);
            p[j][ct] = pe;
            lacc += pe;
          }
          l_lane[j] += lacc;
        }
      }
      // ---- P -> wave-private overlay (stride 72, 16B-aligned b128 reads), PV ----
#pragma unroll
      for (int j = 0; j < 4; j++)
#pragma unroll
        for (int ct = 0; ct < 4; ct++)
          Pw[(l16 * 4 + j) * 72 + ct * 16 + l15] = f2bf_t(p[j][ct]);
      s16x8 pa0 = *(const s16x8*)&Pw[l15 * 72 + l16 * 8];
      s16x8 pa1 = *(const s16x8*)&Pw[l15 * 72 + 32 + l16 * 8];
#pragma unroll
      for (int g = 0; g < 4; g++) {
        s16x8 v0 = *(const s16x8*)&Vsm[(g * 16 + l15) * 72 + l16 * 8];
        s16x8 v1 = *(const s16x8*)&Vsm[(g * 16 + l15) * 72 + 32 + l16 * 8];
        o_acc[g] = MFMA(pa1, v1, MFMA(pa0, v0, o_acc[g]));
      }
      __syncthreads();  // overlay/Vsm/Ksm/Esm reads done before next staging writes
    }
    // ---- epilogue: single 16-lane reduce of l, then x2 = x + attn ----
#pragma unroll
    for (int j = 0; j < 4; j++) {
#pragma unroll
      for (int o = 1; o < 16; o <<= 1) l_lane[j] += __shfl_xor(l_lane[j], o);
    }
#pragma unroll
    for (int g = 0; g < 4; g++)
#pragma unroll
      for (int j = 0; j < 4; j++) {
        int r = qb + l16 * 4 + j;
        int c = h * 64 + g * 16 + l15;
        size_t idx = (size_t)(b * Tt + r) * Dd + c;
        x2[idx] = x[idx] + o_acc[g][j] / l_lane[j];
      }
  }
}

extern "C" void kernel_launch(void* const* d_in, const int* in_sizes, int n_in,
                              void* d_out, int out_size, void* d_ws, size_t ws_size,
                              hipStream_t stream) {
  const float* x     = (const float*)d_in[0];
  const float* wq    = (const float*)d_in[1];
  const float* wk    = (const float*)d_in[2];
  const float* wv    = (const float*)d_in[3];
  const float* Er    = (const float*)d_in[4];
  const float* fc1_w = (const float*)d_in[5];
  const float* fc1_b = (const float*)d_in[6];
  const float* fc2_w = (const float*)d_in[7];
  const float* fc2_b = (const float*)d_in[8];
  const float* ln1_w = (const float*)d_in[9];
  const float* ln1_b = (const float*)d_in[10];
  const float* ln2_w = (const float*)d_in[11];
  const float* ln2_b = (const float*)d_in[12];

  const size_t MB = 1024 * 1024;
  char* ws = (char*)d_ws;
  u16*   h1   = (u16*)ws;                 // 0..8M    ln out (reused for ln2 out)
  u16*   qkv  = (u16*)(ws + 8 * MB);      // 8..32M   dead after attn (V third unused)
  u16*   vtb  = (u16*)(ws + 32 * MB);     // 32..40M  dead after attn
  u16*   erb  = (u16*)(ws + 40 * MB);     // 40..44M  dead after attn
  float* x2   = (float*)(ws + 44 * MB);   // 44..60M  alive to end
  u16*   wqkb = (u16*)(ws + 60 * MB);     // 60..66M  [3072,1024] bf16
  u16*   f1b  = (u16*)(ws + 66 * MB);     // 66..74M  [4096,1024] bf16
  u16*   f2b  = (u16*)(ws + 74 * MB);     // 74..82M  [1024,4096] bf16
  u16*   a1   = (u16*)(ws + 8 * MB);      // 8..40M   overlays qkv+vt (both dead)
  float* out  = (float*)d_out;

  ln_kernel<<<dim3(Bb * Tt), 256, 0, stream>>>(x, ln1_w, ln1_b, h1);
  cvt6_kernel<<<dim3(6656), 256, 0, stream>>>(
      Er, erb, wq, wqkb, wk, wqkb + 1024 * 1024, wv, wqkb + 2 * 1024 * 1024,
      fc1_w, f1b, fc2_w, f2b);
  gemm_bt<0, 128, 32><<<dim3(32, 24), 256, 0, stream>>>(h1, wqkb, nullptr, nullptr, qkv, vtb, Dd, 3072);
  attn_kernel<<<dim3(16, 16, 2), 256, 0, stream>>>(qkv, erb, vtb, x, x2);
  ln_kernel<<<dim3(Bb * Tt), 256, 0, stream>>>(x2, ln2_w, ln2_b, h1);
  gemm_bt<1, 128, 32><<<dim3(32, 32), 256, 0, stream>>>(h1, f1b, fc1_b, nullptr, a1, nullptr, Dd, 4096);
  gemm_bt<2, 64, 64><<<dim3(32, 16), 256, 0, stream>>>(a1, f2b, fc2_b, x2, out, nullptr, 4096, Dd);
}